// Round 13
// baseline (74.187 us; speedup 1.0000x reference)
//
#include <hip/hip_runtime.h>

typedef float v2f __attribute__((ext_vector_type(2)));
typedef float v4f __attribute__((ext_vector_type(4)));
typedef __fp16 h2 __attribute__((ext_vector_type(2)));
typedef __fp16 h4 __attribute__((ext_vector_type(4)));

#define B_ 64
#define T_ 2048
#define D_ 512
#define K_ 8
#define THREADS 256
#define TILE_R 16
#define XPITCH 520   // f16 pitch: 512 + 8 pad
#define LGP 9        // logits-table pitch (f32)
#define APITCH 12    // a-table pitch (f32, 16B-aligned rows)
#define LOG2E 1.44269504088896340736f

__device__ __forceinline__ float dev_exp2(float v) { return __builtin_amdgcn_exp2f(v); }
__device__ __forceinline__ h2 pack2(float a, float b) { return __builtin_amdgcn_cvt_pkrtz(a, b); }

// Kernel 1 (round 13): MFMA pass1.
// Round 11/12 diagnosis: pass1's per-lane dots amplified LDS reads 8-16x
// (512KB per 64KB tile; ~46us chip-wide at ds_read_b128 throughput) -- the
// invariant ~70us wall. MFMA reads each operand element once per fragment:
// ~70KB/tile. Structure per tile: stage 16 rows f16 -> pass1 = 16x16 GEMM
// C = X·W^T via v_mfma_f32_16x16x16_f16 (wave owns a K-quarter, 8 MFMA) ->
// logits partials in LDS -> lane-per-row softmax -> VALU pass2.
// Layouts (gfx908-documented, C verified by learn_hip m89):
//   A[m][k]: m=lane&15, k=(lane>>4)*4+i   B[k][n]: n=lane&15, same k
//   C[m][n]: n=lane&15, m=(lane>>4)*4+j
// LDS ~28KB -> 5 blocks/CU (20 waves/CU); VGPR ~85 (no occupancy force).
template <int NCHUNK_T>
__global__ __launch_bounds__(THREADS) void k1_accum(
    const float* __restrict__ x, const float* __restrict__ attn_w,
    const float* __restrict__ attn_b, float* __restrict__ ax_part,
    float* __restrict__ asum_part) {
  constexpr int RPC = T_ / NCHUNK_T;
  constexpr int TILES = RPC / TILE_R;

  const int blk = blockIdx.x;
  const int b = blk / NCHUNK_T;
  const int chunk = blk % NCHUNK_T;
  const int tid = threadIdx.x;
  const int wave = tid >> 6;
  const int lane = tid & 63;

  __shared__ __align__(16) __fp16 xt[TILE_R * XPITCH];  // 16.6 KB
  __shared__ __align__(16) __fp16 wt[K_ * XPITCH];      // 8.3 KB
  __shared__ float lg[4 * TILE_R * LGP];                // 2.3 KB (per-wave C partials)
  __shared__ __align__(16) float at[TILE_R * APITCH];   // 0.77 KB
  __shared__ float bt[K_];

  // ---- stage W once as f16, pre-scaled by log2e (logits feed only softmax)
  {
    const int k = tid >> 5;
    const int d0 = (tid & 31) * 16;
    const float4* wp = (const float4*)(attn_w + k * D_ + d0);
    const float4 g0 = wp[0], g1 = wp[1], g2 = wp[2], g3 = wp[3];
    h2* wdst = (h2*)(wt + k * XPITCH + d0);
    wdst[0] = pack2(g0.x * LOG2E, g0.y * LOG2E);
    wdst[1] = pack2(g0.z * LOG2E, g0.w * LOG2E);
    wdst[2] = pack2(g1.x * LOG2E, g1.y * LOG2E);
    wdst[3] = pack2(g1.z * LOG2E, g1.w * LOG2E);
    wdst[4] = pack2(g2.x * LOG2E, g2.y * LOG2E);
    wdst[5] = pack2(g2.z * LOG2E, g2.w * LOG2E);
    wdst[6] = pack2(g3.x * LOG2E, g3.y * LOG2E);
    wdst[7] = pack2(g3.z * LOG2E, g3.w * LOG2E);
  }
  if (tid < K_) bt[tid] = attn_b[tid] * LOG2E;

  // pass1 lane constants
  const int m16 = lane & 15;            // A row / B col / C col index
  const int kgrp = lane >> 4;           // 0..3
  const __fp16* arow = xt + m16 * XPITCH;
  const __fp16* brow = wt + (m16 < K_ ? m16 : (K_ - 1)) * XPITCH;  // clamp pad cols
  const int koff = wave * 128 + kgrp * 4;  // wave owns K-quarter (128 d)

  // pass2 lane constants
  const int d0p2 = wave * 128 + lane * 2;

  v2f acc[K_];
#pragma unroll
  for (int k = 0; k < K_; ++k) acc[k] = (v2f){0.f, 0.f};
  v2f asum01 = {0.f, 0.f}, asum23 = {0.f, 0.f}, asum45 = {0.f, 0.f}, asum67 = {0.f, 0.f};

  const float* xbase = x + ((size_t)b * T_ + (size_t)chunk * RPC) * (size_t)D_;
  const int t4 = tid << 2;

  for (int t = 0; t < TILES; ++t) {
    // ---- stage: issue 8 float4 loads (32KB tile), then barrier, pack->LDS
    const float* src = xbase + (size_t)t * TILE_R * D_ + t4;
    const float4 f0 = *(const float4*)(src + 0 * 1024);
    const float4 f1 = *(const float4*)(src + 1 * 1024);
    const float4 f2 = *(const float4*)(src + 2 * 1024);
    const float4 f3 = *(const float4*)(src + 3 * 1024);
    const float4 f4 = *(const float4*)(src + 4 * 1024);
    const float4 f5 = *(const float4*)(src + 5 * 1024);
    const float4 f6 = *(const float4*)(src + 6 * 1024);
    const float4 f7 = *(const float4*)(src + 7 * 1024);

    __syncthreads();  // prev pass2 done with xt; W/bt visible on first iter

#define ST1(i, F)                                                    \
    do {                                                             \
      const int g_ = (i)*1024 + t4;                                  \
      h2* dst_ = (h2*)(xt + (g_ >> 9) * XPITCH + (g_ & 511));        \
      dst_[0] = pack2(F.x, F.y);                                     \
      dst_[1] = pack2(F.z, F.w);                                     \
    } while (0)
    ST1(0, f0); ST1(1, f1); ST1(2, f2); ST1(3, f3);
    ST1(4, f4); ST1(5, f5); ST1(6, f6); ST1(7, f7);
#undef ST1
    __syncthreads();  // xt ready

    // ---- pass1: C = X(16 x 128q) x W^T(128q x 16) via 8 MFMA, K-quarter/wave
    {
      v4f cacc = {0.f, 0.f, 0.f, 0.f};
#pragma unroll
      for (int s = 0; s < 8; ++s) {
        const int k0 = koff + s * 16;
        const h4 av = *(const h4*)(arow + k0);
        const h4 bv = *(const h4*)(brow + k0);
        cacc = __builtin_amdgcn_mfma_f32_16x16x16f16(av, bv, cacc, 0, 0, 0);
      }
      if (m16 < K_) {  // real k columns only
        const int base = (wave * TILE_R + kgrp * 4) * LGP + m16;
#pragma unroll
        for (int j = 0; j < 4; ++j) lg[base + j * LGP] = cacc[j];
      }
    }
    __syncthreads();  // lg ready

    // ---- softmax: lane-per-row, lane-local (exp2 domain, no max-sub:
    //      logits ~ N(0,1), fp32-safe; ratio identical)
    if (wave == 0 && lane < TILE_R) {
      float e[K_];
      float tot = 0.f;
#pragma unroll
      for (int k = 0; k < K_; ++k) {
        const float l = ((lg[(0 * TILE_R + lane) * LGP + k] +
                          lg[(1 * TILE_R + lane) * LGP + k]) +
                         (lg[(2 * TILE_R + lane) * LGP + k] +
                          lg[(3 * TILE_R + lane) * LGP + k])) + bt[k];
        e[k] = dev_exp2(l);
        tot += e[k];
      }
      const float inv = __builtin_amdgcn_rcpf(tot);
      float4* adst = (float4*)(at + lane * APITCH);
      adst[0] = (float4){e[0] * inv, e[1] * inv, e[2] * inv, e[3] * inv};
      adst[1] = (float4){e[4] * inv, e[5] * inv, e[6] * inv, e[7] * inv};
    }
    __syncthreads();  // at ready

    // ---- pass2: acc[k] += a[r][k] * x[r][d-pair]; a reads broadcast
#pragma unroll
    for (int rr = 0; rr < TILE_R; ++rr) {
      const float4 alo = *(const float4*)(at + rr * APITCH);
      const float4 ahi = *(const float4*)(at + rr * APITCH + 4);
      const h2 xp = *(const h2*)(xt + rr * XPITCH + d0p2);
      const v2f xv = {(float)xp[0], (float)xp[1]};
      acc[0] += (v2f){alo.x, alo.x} * xv;
      acc[1] += (v2f){alo.y, alo.y} * xv;
      acc[2] += (v2f){alo.z, alo.z} * xv;
      acc[3] += (v2f){alo.w, alo.w} * xv;
      acc[4] += (v2f){ahi.x, ahi.x} * xv;
      acc[5] += (v2f){ahi.y, ahi.y} * xv;
      acc[6] += (v2f){ahi.z, ahi.z} * xv;
      acc[7] += (v2f){ahi.w, ahi.w} * xv;
      if (wave == 0) {  // wave-uniform broadcast values: track asum once
        asum01 += (v2f){alo.x, alo.y};
        asum23 += (v2f){alo.z, alo.w};
        asum45 += (v2f){ahi.x, ahi.y};
        asum67 += (v2f){ahi.z, ahi.w};
      }
    }
  }

  // ---- write per-chunk partials (coalesced dwordx2)
  float* outp = ax_part + (size_t)blk * (K_ * D_);
#pragma unroll
  for (int k = 0; k < K_; ++k) *(v2f*)(outp + k * D_ + d0p2) = acc[k];
  if (tid == 0) {
    float* ap = asum_part + blk * K_;
    ap[0] = asum01.x; ap[1] = asum01.y; ap[2] = asum23.x; ap[3] = asum23.y;
    ap[4] = asum45.x; ap[5] = asum45.y; ap[6] = asum67.x; ap[7] = asum67.y;
  }
}

// k2a: 4 blocks per batch -> reduce chunks, subtract asum*centers, partial sq
template <int NCHUNK_T>
__global__ __launch_bounds__(256) void k2a(
    const float* __restrict__ ax_part, const float* __restrict__ asum_part,
    const float* __restrict__ centers, float* __restrict__ pbuf,
    float* __restrict__ sqpart) {
  const int b = blockIdx.x >> 2;
  const int q = blockIdx.x & 3;
  const int tid = threadIdx.x;
  __shared__ float s_as[K_];
  __shared__ float s_sq[4];
  if (tid < K_) {
    float s = 0.f;
    for (int c = 0; c < NCHUNK_T; ++c) s += asum_part[(b * NCHUNK_T + c) * K_ + tid];
    s_as[tid] = s;
  }
  __syncthreads();
  const int idx = q * 1024 + tid * 4;
  float4 s = {0.f, 0.f, 0.f, 0.f};
  const float* base = ax_part + (size_t)b * NCHUNK_T * (K_ * D_) + idx;
  for (int c = 0; c < NCHUNK_T; ++c) {
    const float4 v = *(const float4*)(base + (size_t)c * (K_ * D_));
    s.x += v.x; s.y += v.y; s.z += v.z; s.w += v.w;
  }
  const int k = idx >> 9;
  const float a = s_as[k];
  const float4 cv = *(const float4*)(centers + idx);
  float4 p;
  p.x = s.x - a * cv.x; p.y = s.y - a * cv.y;
  p.z = s.z - a * cv.z; p.w = s.w - a * cv.w;
  *(float4*)(pbuf + (size_t)b * (K_ * D_) + idx) = p;
  float sq = p.x * p.x + p.y * p.y + p.z * p.z + p.w * p.w;
#pragma unroll
  for (int m = 32; m; m >>= 1) sq += __shfl_xor(sq, m);
  if ((tid & 63) == 0) s_sq[tid >> 6] = sq;
  __syncthreads();
  if (tid == 0) sqpart[blockIdx.x] = (s_sq[0] + s_sq[1]) + (s_sq[2] + s_sq[3]);
}

// k2b: normalize (pbuf is L2/L3-hot)
__global__ __launch_bounds__(1024) void k2b(const float* __restrict__ pbuf,
                                            const float* __restrict__ sqpart,
                                            float* __restrict__ out) {
  const int b = blockIdx.x;
  const float tot =
      (sqpart[b * 4] + sqpart[b * 4 + 1]) + (sqpart[b * 4 + 2] + sqpart[b * 4 + 3]);
  const float invn = 1.0f / fmaxf(__builtin_sqrtf(tot), 1e-12f);
  const int idx = threadIdx.x * 4;
  const float4 p = *(const float4*)(pbuf + (size_t)b * (K_ * D_) + idx);
  *(float4*)(out + (size_t)b * (K_ * D_) + idx) =
      (float4){p.x * invn, p.y * invn, p.z * invn, p.w * invn};
}

// legacy single-kernel finalize (smallest-workspace fallback)
template <int NCHUNK_T>
__global__ __launch_bounds__(1024) void k2_old(
    const float* __restrict__ ax_part, const float* __restrict__ asum_part,
    const float* __restrict__ centers, float* __restrict__ out) {
  const int b = blockIdx.x;
  const int tid = threadIdx.x;
  const int wave = tid >> 6;
  const int lane = tid & 63;
  __shared__ float s_asum[K_];
  __shared__ float s_sq[16];
  if (tid < K_) {
    float s = 0.f;
    for (int c = 0; c < NCHUNK_T; ++c) s += asum_part[(b * NCHUNK_T + c) * K_ + tid];
    s_asum[tid] = s;
  }
  __syncthreads();
  const int NPT = (K_ * D_) / 1024;
  float pooled[NPT];
  float sq = 0.f;
  const float* base = ax_part + (size_t)b * NCHUNK_T * (K_ * D_);
#pragma unroll
  for (int i = 0; i < NPT; ++i) {
    const int idx = tid + i * 1024;
    float v = 0.f;
    for (int c = 0; c < NCHUNK_T; ++c) v += base[(size_t)c * (K_ * D_) + idx];
    v -= s_asum[idx >> 9] * centers[idx];
    pooled[i] = v;
    sq = fmaf(v, v, sq);
  }
#pragma unroll
  for (int m = 32; m; m >>= 1) sq += __shfl_xor(sq, m);
  if (lane == 0) s_sq[wave] = sq;
  __syncthreads();
  float tot = 0.f;
#pragma unroll
  for (int wv = 0; wv < 16; ++wv) tot += s_sq[wv];
  const float invn = 1.0f / fmaxf(__builtin_sqrtf(tot), 1e-12f);
#pragma unroll
  for (int i = 0; i < NPT; ++i)
    out[(size_t)b * (K_ * D_) + tid + i * 1024] = pooled[i] * invn;
}

extern "C" void kernel_launch(void* const* d_in, const int* in_sizes, int n_in,
                              void* d_out, int out_size, void* d_ws, size_t ws_size,
                              hipStream_t stream) {
  (void)in_sizes; (void)n_in; (void)out_size;
  const float* x = (const float*)d_in[0];
  const float* centers = (const float*)d_in[1];
  const float* attn_w = (const float*)d_in[2];
  const float* attn_b = (const float*)d_in[3];
  float* out = (float*)d_out;

  const size_t KD = (size_t)K_ * D_;
  auto need = [&](int n) {
    return (size_t)B_ * n * KD * 4 + (size_t)B_ * n * K_ * 4 +
           (size_t)B_ * KD * 4 + (size_t)B_ * 4 * 4;
  };

  if (ws_size >= need(32)) {
    float* ax = (float*)d_ws;
    float* as = ax + (size_t)B_ * 32 * KD;
    float* pb = as + (size_t)B_ * 32 * K_;
    float* sp = pb + (size_t)B_ * KD;
    k1_accum<32><<<B_ * 32, THREADS, 0, stream>>>(x, attn_w, attn_b, ax, as);
    k2a<32><<<B_ * 4, 256, 0, stream>>>(ax, as, centers, pb, sp);
    k2b<<<B_, 1024, 0, stream>>>(pb, sp, out);
  } else if (ws_size >= need(16)) {
    float* ax = (float*)d_ws;
    float* as = ax + (size_t)B_ * 16 * KD;
    float* pb = as + (size_t)B_ * 16 * K_;
    float* sp = pb + (size_t)B_ * KD;
    k1_accum<16><<<B_ * 16, THREADS, 0, stream>>>(x, attn_w, attn_b, ax, as);
    k2a<16><<<B_ * 4, 256, 0, stream>>>(ax, as, centers, pb, sp);
    k2b<<<B_, 1024, 0, stream>>>(pb, sp, out);
  } else {
    float* ax = (float*)d_ws;
    float* as = ax + (size_t)B_ * 8 * KD;
    k1_accum<8><<<B_ * 8, THREADS, 0, stream>>>(x, attn_w, attn_b, ax, as);
    k2_old<8><<<B_, 1024, 0, stream>>>(ax, as, centers, out);
  }
}